// Round 1
// baseline (422.038 us; speedup 1.0000x reference)
//
#include <hip/hip_runtime.h>
#include <stdint.h>

// MLP_tcnn: x(524288x64) -> [W0 64x128 relu] -> [W1..W4 128x128 relu] -> [W5 128x16] + bias
// R1: occupancy attack.  Drop the Wbuf LDS stage entirely (weight image is 148 KB,
// L2-resident; A-frags load straight from global).  Shrink block to the minimal
// dependent set: 2 waves / 64-sample tile (waves only exchange H with their partner).
// LDS 64KB -> 16KB per block => ~10 blocks/CU instead of 2; barriers span 2 waves.

typedef __bf16 bf16x8 __attribute__((ext_vector_type(8)));
typedef __bf16 bf16x4 __attribute__((ext_vector_type(4)));
typedef float  floatx4 __attribute__((ext_vector_type(4)));

constexpr int NS   = 524288;   // samples
constexpr int TILE = 64;       // samples per block
constexpr int NBLK = NS / TILE;   // 8192 blocks

// weight image offsets/counts in 16B chunks inside d_ws
// L0: 128 rows x 8 chunks (K=64); L1-4: 128 x 16; L5: 16 x 16
constexpr int WTOT = 9472;     // total chunks = 151552 bytes

__global__ void prep_weights(const float* __restrict__ W0, const float* __restrict__ W1,
                             const float* __restrict__ W2, const float* __restrict__ W3,
                             const float* __restrict__ W4, const float* __restrict__ W5,
                             bf16x8* __restrict__ ws) {
  int gid = blockIdx.x * blockDim.x + threadIdx.x;
  if (gid >= WTOT) return;
  const float* Wsrc; int nout, cpr, base;
  if (gid < 1024)      { Wsrc = W0; nout = 128; cpr = 8;  base = 0;    }
  else if (gid < 3072) { Wsrc = W1; nout = 128; cpr = 16; base = 1024; }
  else if (gid < 5120) { Wsrc = W2; nout = 128; cpr = 16; base = 3072; }
  else if (gid < 7168) { Wsrc = W3; nout = 128; cpr = 16; base = 5120; }
  else if (gid < 9216) { Wsrc = W4; nout = 128; cpr = 16; base = 7168; }
  else                 { Wsrc = W5; nout = 16;  cpr = 16; base = 9216; }
  int id = gid - base;
  int n  = id / cpr;          // out-feature = row of W^T image
  int c  = id % cpr;          // k-chunk (linear: no LDS banks involved anymore)
  bf16x8 v;
#pragma unroll
  for (int j = 0; j < 8; ++j)
    v[j] = (__bf16)Wsrc[(8 * c + j) * nout + n];   // W^T[n][8c+j] = W[8c+j][n]
  ws[gid] = v;
}

__device__ __forceinline__ void zero_acc(floatx4 acc[4][4]) {
  floatx4 z = {0.f, 0.f, 0.f, 0.f};
#pragma unroll
  for (int i = 0; i < 4; ++i)
#pragma unroll
    for (int j = 0; j < 4; ++j) acc[i][j] = z;
}

// one 128-out x 64-sample layer; each wave does a 64-out x 64-sample half.
// A-frags come straight from the global weight image (L1/L2-hot),
// B-frags from the XOR-swizzled sample-major Hbuf in LDS.
// KT = K/32, CPR = chunks per W-image row (K/8).
template <int KT, int CPR>
__device__ __forceinline__ void layer_mm(const bf16x8* __restrict__ Wg, const bf16x8* Hb,
                                         floatx4 acc[4][4], int m_base, int l15, int g) {
#pragma unroll
  for (int kt = 0; kt < KT; ++kt) {
    const int cw = kt * 4 + g;            // logical k-chunk for this lane
    const int cx = cw ^ (l15 & 7);        // Hbuf slot (bank swizzle)
    bf16x8 a[4], b[4];
#pragma unroll
    for (int i = 0; i < 4; ++i) a[i] = Wg[(m_base + 16 * i + l15) * CPR + cw];
#pragma unroll
    for (int i = 0; i < 4; ++i) b[i] = Hb[(16 * i + l15) * 16 + cx];
#pragma unroll
    for (int ot = 0; ot < 4; ++ot)
#pragma unroll
      for (int nt = 0; nt < 4; ++nt)
        acc[ot][nt] = __builtin_amdgcn_mfma_f32_16x16x32_bf16(a[ot], b[nt], acc[ot][nt], 0, 0, 0);
  }
}

// C-frag (col=sample=lane&15, rows = 4g..4g+3 out-features) -> relu -> bf16 -> H (sample-major)
__device__ __forceinline__ void write_h(bf16x4* H8, const floatx4 acc[4][4],
                                        int m_base, int l15, int g) {
#pragma unroll
  for (int ot = 0; ot < 4; ++ot) {
    int ob    = m_base + 16 * ot + 4 * g;                        // out-feature base (4-aligned)
    int phys8 = (((ob >> 3) ^ (l15 & 7)) << 1) | ((ob >> 2) & 1);
#pragma unroll
    for (int nt = 0; nt < 4; ++nt) {
      int s = 16 * nt + l15;                                     // sample row
      floatx4 v = acc[ot][nt];
      bf16x4 h;
      h[0] = (__bf16)fmaxf(v[0], 0.0f);
      h[1] = (__bf16)fmaxf(v[1], 0.0f);
      h[2] = (__bf16)fmaxf(v[2], 0.0f);
      h[3] = (__bf16)fmaxf(v[3], 0.0f);
      H8[s * 32 + phys8] = h;
    }
  }
}

__global__ void __launch_bounds__(128, 5) mlp_kernel(const float* __restrict__ x,
                                                     const float* __restrict__ bias,
                                                     const bf16x8* __restrict__ wimg,
                                                     float* __restrict__ out) {
  __shared__ bf16x8 Hbuf[TILE * 16];   // 16KB: sample-major rows, 16 chunks, XOR-swizzled

  const int t    = threadIdx.x;
  const int lane = t & 63;
  const int w    = t >> 6;             // 0 or 1
  const int l15  = lane & 15;
  const int g    = lane >> 4;
  const int m_base = w * 64;           // out-feature half owned by this wave
  const int tile = blockIdx.x;

  constexpr int WOFF[6] = {0, 1024, 3072, 5120, 7168, 9216};

  // stage x tile -> Hbuf (fp32 -> bf16), one 16B chunk (8 feats of one sample) per iter
  const float* xt = x + (size_t)tile * TILE * 64;
#pragma unroll
  for (int i = 0; i < 4; ++i) {
    int f2 = t + 128 * i;              // chunk id 0..511
    int s = f2 >> 3, c = f2 & 7;
    const floatx4* src = (const floatx4*)(xt + f2 * 8);
    floatx4 lo = src[0], hi = src[1];
    bf16x8 v;
    v[0] = (__bf16)lo[0]; v[1] = (__bf16)lo[1]; v[2] = (__bf16)lo[2]; v[3] = (__bf16)lo[3];
    v[4] = (__bf16)hi[0]; v[5] = (__bf16)hi[1]; v[6] = (__bf16)hi[2]; v[7] = (__bf16)hi[3];
    Hbuf[s * 16 + (c ^ (s & 7))] = v;
  }
  __syncthreads();

  floatx4 acc[4][4];

  // ---- layer 0: K=64 ----
  zero_acc(acc);
  layer_mm<2, 8>(wimg + WOFF[0], Hbuf, acc, m_base, l15, g);
  __syncthreads();                                   // all Hbuf reads done
  write_h((bf16x4*)Hbuf, acc, m_base, l15, g);
  __syncthreads();

  // ---- layers 1..4: K=128 ----
#pragma unroll
  for (int l = 1; l <= 4; ++l) {
    zero_acc(acc);
    layer_mm<4, 16>(wimg + WOFF[l], Hbuf, acc, m_base, l15, g);
    __syncthreads();
    write_h((bf16x4*)Hbuf, acc, m_base, l15, g);
    __syncthreads();
  }

  // ---- layer 5: M=16, K=128, no relu, + bias, store fp32 ----
  const bf16x8* W5g = wimg + WOFF[5];
  floatx4 a5[2];
  {
    floatx4 z = {0.f, 0.f, 0.f, 0.f};
    a5[0] = z; a5[1] = z;
  }
  const int n5 = w * 32;               // each wave: 32 samples, all 16 out-features
#pragma unroll
  for (int kt = 0; kt < 4; ++kt) {
    int cw = kt * 4 + g;
    int cx = cw ^ (l15 & 7);
    bf16x8 a = W5g[l15 * 16 + cw];     // W5^T row = out-feature l15 (global, L2-hot)
#pragma unroll
    for (int nt = 0; nt < 2; ++nt) {
      bf16x8 b = Hbuf[(n5 + 16 * nt + l15) * 16 + cx];
      a5[nt] = __builtin_amdgcn_mfma_f32_16x16x32_bf16(a, b, a5[nt], 0, 0, 0);
    }
  }
  floatx4 bv = *(const floatx4*)(bias + 4 * g);
  floatx4* outv = (floatx4*)out;
#pragma unroll
  for (int nt = 0; nt < 2; ++nt) {
    int s = tile * TILE + n5 + 16 * nt + l15;
    outv[s * 4 + g] = a5[nt] + bv;     // wave's 8 stores cover 1KB contiguous
  }
}

extern "C" void kernel_launch(void* const* d_in, const int* in_sizes, int n_in,
                              void* d_out, int out_size, void* d_ws, size_t ws_size,
                              hipStream_t stream) {
  (void)in_sizes; (void)n_in; (void)out_size; (void)ws_size;
  const float* x    = (const float*)d_in[0];
  const float* W0   = (const float*)d_in[1];
  const float* W1   = (const float*)d_in[2];
  const float* W2   = (const float*)d_in[3];
  const float* W3   = (const float*)d_in[4];
  const float* W4   = (const float*)d_in[5];
  const float* W5   = (const float*)d_in[6];
  const float* bias = (const float*)d_in[7];
  bf16x8* ws = (bf16x8*)d_ws;   // needs 151552 B

  prep_weights<<<(WTOT + 255) / 256, 256, 0, stream>>>(W0, W1, W2, W3, W4, W5, ws);
  mlp_kernel<<<NBLK, 128, 0, stream>>>(x, bias, (const bf16x8*)ws, (float*)d_out);
}

// Round 2
// 349.507 us; speedup vs baseline: 1.2075x; 1.2075x over previous
//
#include <hip/hip_runtime.h>
#include <stdint.h>

// MLP_tcnn: x(524288x64) -> [W0 64x128 relu] -> [W1..W4 128x128 relu] -> [W5 128x16] + bias
// R2: fix R1's spill. R1's __launch_bounds__(128,5) capped VGPRs at ~102 < ~115 live
// => acc spilled to scratch (VGPR_Count 48, WRITE_SIZE 357MB). Relax to (128,4):
// 128-VGPR budget, no spill, still 4 waves/SIMD = 8 blocks/CU (50% occ, vs R0's 20%).
// Structure unchanged from R1: 2-wave / 64-sample blocks, no Wbuf (weights from L1/L2),
// 16KB LDS Hbuf, XOR bank swizzle.

typedef __bf16 bf16x8 __attribute__((ext_vector_type(8)));
typedef __bf16 bf16x4 __attribute__((ext_vector_type(4)));
typedef float  floatx4 __attribute__((ext_vector_type(4)));

constexpr int NS   = 524288;   // samples
constexpr int TILE = 64;       // samples per block
constexpr int NBLK = NS / TILE;   // 8192 blocks

// weight image offsets/counts in 16B chunks inside d_ws
// L0: 128 rows x 8 chunks (K=64); L1-4: 128 x 16; L5: 16 x 16
constexpr int WTOT = 9472;     // total chunks = 151552 bytes

__global__ void prep_weights(const float* __restrict__ W0, const float* __restrict__ W1,
                             const float* __restrict__ W2, const float* __restrict__ W3,
                             const float* __restrict__ W4, const float* __restrict__ W5,
                             bf16x8* __restrict__ ws) {
  int gid = blockIdx.x * blockDim.x + threadIdx.x;
  if (gid >= WTOT) return;
  const float* Wsrc; int nout, cpr, base;
  if (gid < 1024)      { Wsrc = W0; nout = 128; cpr = 8;  base = 0;    }
  else if (gid < 3072) { Wsrc = W1; nout = 128; cpr = 16; base = 1024; }
  else if (gid < 5120) { Wsrc = W2; nout = 128; cpr = 16; base = 3072; }
  else if (gid < 7168) { Wsrc = W3; nout = 128; cpr = 16; base = 5120; }
  else if (gid < 9216) { Wsrc = W4; nout = 128; cpr = 16; base = 7168; }
  else                 { Wsrc = W5; nout = 16;  cpr = 16; base = 9216; }
  int id = gid - base;
  int n  = id / cpr;          // out-feature = row of W^T image
  int c  = id % cpr;          // k-chunk (linear layout in global)
  bf16x8 v;
#pragma unroll
  for (int j = 0; j < 8; ++j)
    v[j] = (__bf16)Wsrc[(8 * c + j) * nout + n];   // W^T[n][8c+j] = W[8c+j][n]
  ws[gid] = v;
}

__device__ __forceinline__ void zero_acc(floatx4 acc[4][4]) {
  floatx4 z = {0.f, 0.f, 0.f, 0.f};
#pragma unroll
  for (int i = 0; i < 4; ++i)
#pragma unroll
    for (int j = 0; j < 4; ++j) acc[i][j] = z;
}

// one 128-out x 64-sample layer; each wave does a 64-out x 64-sample half.
// A-frags come straight from the global weight image (L1/L2-hot),
// B-frags from the XOR-swizzled sample-major Hbuf in LDS.
// KT = K/32, CPR = chunks per W-image row (K/8).
template <int KT, int CPR>
__device__ __forceinline__ void layer_mm(const bf16x8* __restrict__ Wg, const bf16x8* Hb,
                                         floatx4 acc[4][4], int m_base, int l15, int g) {
#pragma unroll
  for (int kt = 0; kt < KT; ++kt) {
    const int cw = kt * 4 + g;            // logical k-chunk for this lane
    const int cx = cw ^ (l15 & 7);        // Hbuf slot (bank swizzle)
    bf16x8 a[4], b[4];
#pragma unroll
    for (int i = 0; i < 4; ++i) a[i] = Wg[(m_base + 16 * i + l15) * CPR + cw];
#pragma unroll
    for (int i = 0; i < 4; ++i) b[i] = Hb[(16 * i + l15) * 16 + cx];
#pragma unroll
    for (int ot = 0; ot < 4; ++ot)
#pragma unroll
      for (int nt = 0; nt < 4; ++nt)
        acc[ot][nt] = __builtin_amdgcn_mfma_f32_16x16x32_bf16(a[ot], b[nt], acc[ot][nt], 0, 0, 0);
  }
}

// C-frag (col=sample=lane&15, rows = 4g..4g+3 out-features) -> relu -> bf16 -> H (sample-major)
__device__ __forceinline__ void write_h(bf16x4* H8, const floatx4 acc[4][4],
                                        int m_base, int l15, int g) {
#pragma unroll
  for (int ot = 0; ot < 4; ++ot) {
    int ob    = m_base + 16 * ot + 4 * g;                        // out-feature base (4-aligned)
    int phys8 = (((ob >> 3) ^ (l15 & 7)) << 1) | ((ob >> 2) & 1);
#pragma unroll
    for (int nt = 0; nt < 4; ++nt) {
      int s = 16 * nt + l15;                                     // sample row
      floatx4 v = acc[ot][nt];
      bf16x4 h;
      h[0] = (__bf16)fmaxf(v[0], 0.0f);
      h[1] = (__bf16)fmaxf(v[1], 0.0f);
      h[2] = (__bf16)fmaxf(v[2], 0.0f);
      h[3] = (__bf16)fmaxf(v[3], 0.0f);
      H8[s * 32 + phys8] = h;
    }
  }
}

__global__ void __launch_bounds__(128, 4) mlp_kernel(const float* __restrict__ x,
                                                     const float* __restrict__ bias,
                                                     const bf16x8* __restrict__ wimg,
                                                     float* __restrict__ out) {
  __shared__ bf16x8 Hbuf[TILE * 16];   // 16KB: sample-major rows, 16 chunks, XOR-swizzled

  const int t    = threadIdx.x;
  const int lane = t & 63;
  const int w    = t >> 6;             // 0 or 1
  const int l15  = lane & 15;
  const int g    = lane >> 4;
  const int m_base = w * 64;           // out-feature half owned by this wave
  const int tile = blockIdx.x;

  constexpr int WOFF[6] = {0, 1024, 3072, 5120, 7168, 9216};

  // stage x tile -> Hbuf (fp32 -> bf16), one 16B chunk (8 feats of one sample) per iter
  const float* xt = x + (size_t)tile * TILE * 64;
#pragma unroll
  for (int i = 0; i < 4; ++i) {
    int f2 = t + 128 * i;              // chunk id 0..511
    int s = f2 >> 3, c = f2 & 7;
    const floatx4* src = (const floatx4*)(xt + f2 * 8);
    floatx4 lo = src[0], hi = src[1];
    bf16x8 v;
    v[0] = (__bf16)lo[0]; v[1] = (__bf16)lo[1]; v[2] = (__bf16)lo[2]; v[3] = (__bf16)lo[3];
    v[4] = (__bf16)hi[0]; v[5] = (__bf16)hi[1]; v[6] = (__bf16)hi[2]; v[7] = (__bf16)hi[3];
    Hbuf[s * 16 + (c ^ (s & 7))] = v;
  }
  __syncthreads();

  floatx4 acc[4][4];

  // ---- layer 0: K=64 ----
  zero_acc(acc);
  layer_mm<2, 8>(wimg + WOFF[0], Hbuf, acc, m_base, l15, g);
  __syncthreads();                                   // all Hbuf reads done
  write_h((bf16x4*)Hbuf, acc, m_base, l15, g);
  __syncthreads();

  // ---- layers 1..4: K=128 ----
#pragma unroll
  for (int l = 1; l <= 4; ++l) {
    zero_acc(acc);
    layer_mm<4, 16>(wimg + WOFF[l], Hbuf, acc, m_base, l15, g);
    __syncthreads();
    write_h((bf16x4*)Hbuf, acc, m_base, l15, g);
    __syncthreads();
  }

  // ---- layer 5: M=16, K=128, no relu, + bias, store fp32 ----
  const bf16x8* W5g = wimg + WOFF[5];
  floatx4 a5[2];
  {
    floatx4 z = {0.f, 0.f, 0.f, 0.f};
    a5[0] = z; a5[1] = z;
  }
  const int n5 = w * 32;               // each wave: 32 samples, all 16 out-features
#pragma unroll
  for (int kt = 0; kt < 4; ++kt) {
    int cw = kt * 4 + g;
    int cx = cw ^ (l15 & 7);
    bf16x8 a = W5g[l15 * 16 + cw];     // W5^T row = out-feature l15 (global, L2-hot)
#pragma unroll
    for (int nt = 0; nt < 2; ++nt) {
      bf16x8 b = Hbuf[(n5 + 16 * nt + l15) * 16 + cx];
      a5[nt] = __builtin_amdgcn_mfma_f32_16x16x32_bf16(a, b, a5[nt], 0, 0, 0);
    }
  }
  floatx4 bv = *(const floatx4*)(bias + 4 * g);
  floatx4* outv = (floatx4*)out;
#pragma unroll
  for (int nt = 0; nt < 2; ++nt) {
    int s = tile * TILE + n5 + 16 * nt + l15;
    outv[s * 4 + g] = a5[nt] + bv;     // wave's 8 stores cover 1KB contiguous
  }
}

extern "C" void kernel_launch(void* const* d_in, const int* in_sizes, int n_in,
                              void* d_out, int out_size, void* d_ws, size_t ws_size,
                              hipStream_t stream) {
  (void)in_sizes; (void)n_in; (void)out_size; (void)ws_size;
  const float* x    = (const float*)d_in[0];
  const float* W0   = (const float*)d_in[1];
  const float* W1   = (const float*)d_in[2];
  const float* W2   = (const float*)d_in[3];
  const float* W3   = (const float*)d_in[4];
  const float* W4   = (const float*)d_in[5];
  const float* W5   = (const float*)d_in[6];
  const float* bias = (const float*)d_in[7];
  bf16x8* ws = (bf16x8*)d_ws;   // needs 151552 B

  prep_weights<<<(WTOT + 255) / 256, 256, 0, stream>>>(W0, W1, W2, W3, W4, W5, ws);
  mlp_kernel<<<NBLK, 128, 0, stream>>>(x, bias, (const bf16x8*)ws, (float*)d_out);
}

// Round 3
// 338.126 us; speedup vs baseline: 1.2482x; 1.0337x over previous
//
#include <hip/hip_runtime.h>
#include <stdint.h>

// MLP_tcnn: x(524288x64) -> [W0 64x128 relu] -> [W1..W4 128x128 relu] -> [W5 128x16] + bias
// R3: fix the spill properly. gfx950 has a UNIFIED VGPR/AGPR file, so
// __launch_bounds__(128,4)'s 128-reg cap had to cover the 64-AGPR accumulator too ->
// only 64 arch VGPRs -> spill (R2: VGPR_Count=64, WRITE_SIZE 117MB vs 33.5MB output).
// R0's natural allocation was 88 arch + 64 acc = 152 total, so cap one step higher:
// __launch_bounds__(128,3) -> ~168-reg budget, no spill, 3 waves/SIMD = 6 blocks/CU
// (37.5% occ vs R0's 20%). Structure unchanged: 2-wave / 64-sample blocks, no Wbuf
// (weights from L1/L2), 16KB LDS Hbuf, XOR bank swizzle.

typedef __bf16 bf16x8 __attribute__((ext_vector_type(8)));
typedef __bf16 bf16x4 __attribute__((ext_vector_type(4)));
typedef float  floatx4 __attribute__((ext_vector_type(4)));

constexpr int NS   = 524288;   // samples
constexpr int TILE = 64;       // samples per block
constexpr int NBLK = NS / TILE;   // 8192 blocks

// weight image offsets/counts in 16B chunks inside d_ws
// L0: 128 rows x 8 chunks (K=64); L1-4: 128 x 16; L5: 16 x 16
constexpr int WTOT = 9472;     // total chunks = 151552 bytes

__global__ void prep_weights(const float* __restrict__ W0, const float* __restrict__ W1,
                             const float* __restrict__ W2, const float* __restrict__ W3,
                             const float* __restrict__ W4, const float* __restrict__ W5,
                             bf16x8* __restrict__ ws) {
  int gid = blockIdx.x * blockDim.x + threadIdx.x;
  if (gid >= WTOT) return;
  const float* Wsrc; int nout, cpr, base;
  if (gid < 1024)      { Wsrc = W0; nout = 128; cpr = 8;  base = 0;    }
  else if (gid < 3072) { Wsrc = W1; nout = 128; cpr = 16; base = 1024; }
  else if (gid < 5120) { Wsrc = W2; nout = 128; cpr = 16; base = 3072; }
  else if (gid < 7168) { Wsrc = W3; nout = 128; cpr = 16; base = 5120; }
  else if (gid < 9216) { Wsrc = W4; nout = 128; cpr = 16; base = 7168; }
  else                 { Wsrc = W5; nout = 16;  cpr = 16; base = 9216; }
  int id = gid - base;
  int n  = id / cpr;          // out-feature = row of W^T image
  int c  = id % cpr;          // k-chunk (linear layout in global)
  bf16x8 v;
#pragma unroll
  for (int j = 0; j < 8; ++j)
    v[j] = (__bf16)Wsrc[(8 * c + j) * nout + n];   // W^T[n][8c+j] = W[8c+j][n]
  ws[gid] = v;
}

__device__ __forceinline__ void zero_acc(floatx4 acc[4][4]) {
  floatx4 z = {0.f, 0.f, 0.f, 0.f};
#pragma unroll
  for (int i = 0; i < 4; ++i)
#pragma unroll
    for (int j = 0; j < 4; ++j) acc[i][j] = z;
}

// one 128-out x 64-sample layer; each wave does a 64-out x 64-sample half.
// A-frags come straight from the global weight image (L1/L2-hot),
// B-frags from the XOR-swizzled sample-major Hbuf in LDS.
// KT = K/32, CPR = chunks per W-image row (K/8).
template <int KT, int CPR>
__device__ __forceinline__ void layer_mm(const bf16x8* __restrict__ Wg, const bf16x8* Hb,
                                         floatx4 acc[4][4], int m_base, int l15, int g) {
#pragma unroll
  for (int kt = 0; kt < KT; ++kt) {
    const int cw = kt * 4 + g;            // logical k-chunk for this lane
    const int cx = cw ^ (l15 & 7);        // Hbuf slot (bank swizzle)
    bf16x8 a[4], b[4];
#pragma unroll
    for (int i = 0; i < 4; ++i) a[i] = Wg[(m_base + 16 * i + l15) * CPR + cw];
#pragma unroll
    for (int i = 0; i < 4; ++i) b[i] = Hb[(16 * i + l15) * 16 + cx];
#pragma unroll
    for (int ot = 0; ot < 4; ++ot)
#pragma unroll
      for (int nt = 0; nt < 4; ++nt)
        acc[ot][nt] = __builtin_amdgcn_mfma_f32_16x16x32_bf16(a[ot], b[nt], acc[ot][nt], 0, 0, 0);
  }
}

// C-frag (col=sample=lane&15, rows = 4g..4g+3 out-features) -> relu -> bf16 -> H (sample-major)
__device__ __forceinline__ void write_h(bf16x4* H8, const floatx4 acc[4][4],
                                        int m_base, int l15, int g) {
#pragma unroll
  for (int ot = 0; ot < 4; ++ot) {
    int ob    = m_base + 16 * ot + 4 * g;                        // out-feature base (4-aligned)
    int phys8 = (((ob >> 3) ^ (l15 & 7)) << 1) | ((ob >> 2) & 1);
#pragma unroll
    for (int nt = 0; nt < 4; ++nt) {
      int s = 16 * nt + l15;                                     // sample row
      floatx4 v = acc[ot][nt];
      bf16x4 h;
      h[0] = (__bf16)fmaxf(v[0], 0.0f);
      h[1] = (__bf16)fmaxf(v[1], 0.0f);
      h[2] = (__bf16)fmaxf(v[2], 0.0f);
      h[3] = (__bf16)fmaxf(v[3], 0.0f);
      H8[s * 32 + phys8] = h;
    }
  }
}

__global__ void __launch_bounds__(128, 3) mlp_kernel(const float* __restrict__ x,
                                                     const float* __restrict__ bias,
                                                     const bf16x8* __restrict__ wimg,
                                                     float* __restrict__ out) {
  __shared__ bf16x8 Hbuf[TILE * 16];   // 16KB: sample-major rows, 16 chunks, XOR-swizzled

  const int t    = threadIdx.x;
  const int lane = t & 63;
  const int w    = t >> 6;             // 0 or 1
  const int l15  = lane & 15;
  const int g    = lane >> 4;
  const int m_base = w * 64;           // out-feature half owned by this wave
  const int tile = blockIdx.x;

  constexpr int WOFF[6] = {0, 1024, 3072, 5120, 7168, 9216};

  // stage x tile -> Hbuf (fp32 -> bf16), one 16B chunk (8 feats of one sample) per iter
  const float* xt = x + (size_t)tile * TILE * 64;
#pragma unroll
  for (int i = 0; i < 4; ++i) {
    int f2 = t + 128 * i;              // chunk id 0..511
    int s = f2 >> 3, c = f2 & 7;
    const floatx4* src = (const floatx4*)(xt + f2 * 8);
    floatx4 lo = src[0], hi = src[1];
    bf16x8 v;
    v[0] = (__bf16)lo[0]; v[1] = (__bf16)lo[1]; v[2] = (__bf16)lo[2]; v[3] = (__bf16)lo[3];
    v[4] = (__bf16)hi[0]; v[5] = (__bf16)hi[1]; v[6] = (__bf16)hi[2]; v[7] = (__bf16)hi[3];
    Hbuf[s * 16 + (c ^ (s & 7))] = v;
  }
  __syncthreads();

  floatx4 acc[4][4];

  // ---- layer 0: K=64 ----
  zero_acc(acc);
  layer_mm<2, 8>(wimg + WOFF[0], Hbuf, acc, m_base, l15, g);
  __syncthreads();                                   // all Hbuf reads done
  write_h((bf16x4*)Hbuf, acc, m_base, l15, g);
  __syncthreads();

  // ---- layers 1..4: K=128 ----
#pragma unroll
  for (int l = 1; l <= 4; ++l) {
    zero_acc(acc);
    layer_mm<4, 16>(wimg + WOFF[l], Hbuf, acc, m_base, l15, g);
    __syncthreads();
    write_h((bf16x4*)Hbuf, acc, m_base, l15, g);
    __syncthreads();
  }

  // ---- layer 5: M=16, K=128, no relu, + bias, store fp32 ----
  const bf16x8* W5g = wimg + WOFF[5];
  floatx4 a5[2];
  {
    floatx4 z = {0.f, 0.f, 0.f, 0.f};
    a5[0] = z; a5[1] = z;
  }
  const int n5 = w * 32;               // each wave: 32 samples, all 16 out-features
#pragma unroll
  for (int kt = 0; kt < 4; ++kt) {
    int cw = kt * 4 + g;
    int cx = cw ^ (l15 & 7);
    bf16x8 a = W5g[l15 * 16 + cw];     // W5^T row = out-feature l15 (global, L2-hot)
#pragma unroll
    for (int nt = 0; nt < 2; ++nt) {
      bf16x8 b = Hbuf[(n5 + 16 * nt + l15) * 16 + cx];
      a5[nt] = __builtin_amdgcn_mfma_f32_16x16x32_bf16(a, b, a5[nt], 0, 0, 0);
    }
  }
  floatx4 bv = *(const floatx4*)(bias + 4 * g);
  floatx4* outv = (floatx4*)out;
#pragma unroll
  for (int nt = 0; nt < 2; ++nt) {
    int s = tile * TILE + n5 + 16 * nt + l15;
    outv[s * 4 + g] = a5[nt] + bv;     // wave's 8 stores cover 1KB contiguous
  }
}

extern "C" void kernel_launch(void* const* d_in, const int* in_sizes, int n_in,
                              void* d_out, int out_size, void* d_ws, size_t ws_size,
                              hipStream_t stream) {
  (void)in_sizes; (void)n_in; (void)out_size; (void)ws_size;
  const float* x    = (const float*)d_in[0];
  const float* W0   = (const float*)d_in[1];
  const float* W1   = (const float*)d_in[2];
  const float* W2   = (const float*)d_in[3];
  const float* W3   = (const float*)d_in[4];
  const float* W4   = (const float*)d_in[5];
  const float* W5   = (const float*)d_in[6];
  const float* bias = (const float*)d_in[7];
  bf16x8* ws = (bf16x8*)d_ws;   // needs 151552 B

  prep_weights<<<(WTOT + 255) / 256, 256, 0, stream>>>(W0, W1, W2, W3, W4, W5, ws);
  mlp_kernel<<<NBLK, 128, 0, stream>>>(x, bias, (const bf16x8*)ws, (float*)d_out);
}

// Round 5
// 269.702 us; speedup vs baseline: 1.5648x; 1.2537x over previous
//
#include <hip/hip_runtime.h>
#include <stdint.h>

// MLP_tcnn: x(524288x64) -> [W0 64x128 relu] -> [W1..W4 128x128 relu] -> [W5 128x16] + bias
// R5 == R4 resubmit (R4 bench died on container acquisition, no dispatch ran).
// R4: split operand traffic across pipes.
//  - R0 was LDS-BW-bound: A+B+Hwrite = ~34KB/wave-layer through one 85 B/cyc pipe vs
//    ~310 cyc of MFMA.  R1-R3 moved A to global but with 256B-strided gathers (64 lines
//    per wave-load) -> TA/L1 throughput-bound (MfmaUtil 17%).
//  - Now: W image stored FRAG-LINEAR in global (prep writes each 1KB MFMA A-fragment in
//    lane order), so A-loads are coalesced global_load_dwordx4 from the L1/L2-hot 148KB
//    image.  B stays in LDS (16KB/wave-layer, under the LDS ceiling).
//  - Hbuf double-buffered (2x16KB): write_h targets the other buffer -> ONE barrier per
//    layer.  2-wave blocks, launch_bounds(128,3); LDS caps occupancy at 5 blocks/CU.

typedef __bf16 bf16x8 __attribute__((ext_vector_type(8)));
typedef __bf16 bf16x4 __attribute__((ext_vector_type(4)));
typedef float  floatx4 __attribute__((ext_vector_type(4)));

constexpr int NS   = 524288;      // samples
constexpr int TILE = 64;          // samples per block
constexpr int NBLK = NS / TILE;   // 8192 blocks

// weight image in 16B chunks inside d_ws, FRAG-LINEAR:
// layer -> frags (rb-major, kt-minor) -> 64 lanes x 16B.
// frag(rb,kt) lane l holds W^T[row=rb*16+(l&15)][k-chunk kt*4+(l>>4)]
// L0: 8rb x 2kt = 16 frags; L1-4: 8 x 4 = 32 frags; L5: 1 x 4 = 4 frags
constexpr int WTOT = 9472;        // total 16B chunks = 151552 bytes

__global__ void prep_weights(const float* __restrict__ W0, const float* __restrict__ W1,
                             const float* __restrict__ W2, const float* __restrict__ W3,
                             const float* __restrict__ W4, const float* __restrict__ W5,
                             bf16x8* __restrict__ ws) {
  int gid = blockIdx.x * blockDim.x + threadIdx.x;
  if (gid >= WTOT) return;
  const float* Wsrc; int nout, kt_n, base;
  if (gid < 1024)      { Wsrc = W0; nout = 128; kt_n = 2; base = 0;    }
  else if (gid < 3072) { Wsrc = W1; nout = 128; kt_n = 4; base = 1024; }
  else if (gid < 5120) { Wsrc = W2; nout = 128; kt_n = 4; base = 3072; }
  else if (gid < 7168) { Wsrc = W3; nout = 128; kt_n = 4; base = 5120; }
  else if (gid < 9216) { Wsrc = W4; nout = 128; kt_n = 4; base = 7168; }
  else                 { Wsrc = W5; nout = 16;  kt_n = 4; base = 9216; }
  int id   = gid - base;
  int lane = id & 63;
  int frag = id >> 6;
  int kt   = frag % kt_n;
  int rb   = frag / kt_n;
  int row   = rb * 16 + (lane & 15);        // out-feature
  int chunk = kt * 4 + (lane >> 4);         // k-chunk (8 k-elems)
  bf16x8 v;
#pragma unroll
  for (int j = 0; j < 8; ++j)
    v[j] = (__bf16)Wsrc[(8 * chunk + j) * nout + row];   // W^T[row][8*chunk+j]
  ws[gid] = v;
}

__device__ __forceinline__ void zero_acc(floatx4 acc[4][4]) {
  floatx4 z = {0.f, 0.f, 0.f, 0.f};
#pragma unroll
  for (int i = 0; i < 4; ++i)
#pragma unroll
    for (int j = 0; j < 4; ++j) acc[i][j] = z;
}

// one 128-out x 64-sample layer; each wave does a 64-out x 64-sample half.
// A-frags: coalesced (lane-linear) loads from the frag-linear global W image.
// B-frags: XOR-swizzled sample-major Hbuf in LDS.
template <int KT>
__device__ __forceinline__ void layer_mm(const bf16x8* __restrict__ Wg, const bf16x8* Hb,
                                         floatx4 acc[4][4], int w, int lane, int l15, int g) {
#pragma unroll
  for (int kt = 0; kt < KT; ++kt) {
    const int cx = (kt * 4 + g) ^ (l15 & 7);   // Hbuf slot (bank swizzle)
    bf16x8 a[4], b[4];
#pragma unroll
    for (int i = 0; i < 4; ++i)
      a[i] = Wg[((4 * w + i) * KT + kt) * 64 + lane];     // 1KB coalesced frag
#pragma unroll
    for (int i = 0; i < 4; ++i) b[i] = Hb[(16 * i + l15) * 16 + cx];
#pragma unroll
    for (int ot = 0; ot < 4; ++ot)
#pragma unroll
      for (int nt = 0; nt < 4; ++nt)
        acc[ot][nt] = __builtin_amdgcn_mfma_f32_16x16x32_bf16(a[ot], b[nt], acc[ot][nt], 0, 0, 0);
  }
}

// C-frag (col=sample=lane&15, rows = 4g..4g+3 out-features) -> relu -> bf16 -> H (sample-major)
__device__ __forceinline__ void write_h(bf16x4* H8, const floatx4 acc[4][4],
                                        int m_base, int l15, int g) {
#pragma unroll
  for (int ot = 0; ot < 4; ++ot) {
    int ob    = m_base + 16 * ot + 4 * g;                        // out-feature base (4-aligned)
    int phys8 = (((ob >> 3) ^ (l15 & 7)) << 1) | ((ob >> 2) & 1);
#pragma unroll
    for (int nt = 0; nt < 4; ++nt) {
      int s = 16 * nt + l15;                                     // sample row
      floatx4 v = acc[ot][nt];
      bf16x4 h;
      h[0] = (__bf16)fmaxf(v[0], 0.0f);
      h[1] = (__bf16)fmaxf(v[1], 0.0f);
      h[2] = (__bf16)fmaxf(v[2], 0.0f);
      h[3] = (__bf16)fmaxf(v[3], 0.0f);
      H8[s * 32 + phys8] = h;
    }
  }
}

__global__ void __launch_bounds__(128, 3) mlp_kernel(const float* __restrict__ x,
                                                     const float* __restrict__ bias,
                                                     const bf16x8* __restrict__ wimg,
                                                     float* __restrict__ out) {
  __shared__ bf16x8 Hbuf[2 * TILE * 16];   // 2 x 16KB: double-buffered, sample-major, swizzled

  bf16x8* H0 = Hbuf;
  bf16x8* H1 = Hbuf + TILE * 16;

  const int t    = threadIdx.x;
  const int lane = t & 63;
  const int w    = t >> 6;             // 0 or 1
  const int l15  = lane & 15;
  const int g    = lane >> 4;
  const int m_base = w * 64;           // out-feature half owned by this wave
  const int tile = blockIdx.x;

  constexpr int WOFF[6] = {0, 1024, 3072, 5120, 7168, 9216};

  // stage x tile -> H0 (fp32 -> bf16), one 16B chunk (8 feats of one sample) per iter
  const float* xt = x + (size_t)tile * TILE * 64;
#pragma unroll
  for (int i = 0; i < 4; ++i) {
    int f2 = t + 128 * i;              // chunk id 0..511
    int s = f2 >> 3, c = f2 & 7;
    const floatx4* src = (const floatx4*)(xt + f2 * 8);
    floatx4 lo = src[0], hi = src[1];
    bf16x8 v;
    v[0] = (__bf16)lo[0]; v[1] = (__bf16)lo[1]; v[2] = (__bf16)lo[2]; v[3] = (__bf16)lo[3];
    v[4] = (__bf16)hi[0]; v[5] = (__bf16)hi[1]; v[6] = (__bf16)hi[2]; v[7] = (__bf16)hi[3];
    H0[s * 16 + (c ^ (s & 7))] = v;
  }
  __syncthreads();

  floatx4 acc[4][4];

  // ---- layer 0: K=64, reads H0, writes H1 ----
  zero_acc(acc);
  layer_mm<2>(wimg + WOFF[0], H0, acc, w, lane, l15, g);
  write_h((bf16x4*)H1, acc, m_base, l15, g);
  __syncthreads();

  // ---- layers 1..4: K=128, ping-pong H1 -> H0 -> H1 ... ----
#pragma unroll
  for (int l = 1; l <= 4; ++l) {
    const bf16x8* Hr = (l & 1) ? H1 : H0;      // compile-time (unrolled)
    bf16x4*       Hw = (l & 1) ? (bf16x4*)H0 : (bf16x4*)H1;
    zero_acc(acc);
    layer_mm<4>(wimg + WOFF[l], Hr, acc, w, lane, l15, g);
    write_h(Hw, acc, m_base, l15, g);
    __syncthreads();
  }

  // ---- layer 5: M=16, K=128, reads H1, no relu, + bias, store fp32 ----
  const bf16x8* W5g = wimg + WOFF[5];
  floatx4 a5[2];
  {
    floatx4 z = {0.f, 0.f, 0.f, 0.f};
    a5[0] = z; a5[1] = z;
  }
  const int n5 = w * 32;               // each wave: 32 samples, all 16 out-features
#pragma unroll
  for (int kt = 0; kt < 4; ++kt) {
    int cx = (kt * 4 + g) ^ (l15 & 7);
    bf16x8 a = W5g[kt * 64 + lane];    // frag-linear, coalesced
#pragma unroll
    for (int nt = 0; nt < 2; ++nt) {
      bf16x8 b = H1[(n5 + 16 * nt + l15) * 16 + cx];
      a5[nt] = __builtin_amdgcn_mfma_f32_16x16x32_bf16(a, b, a5[nt], 0, 0, 0);
    }
  }
  floatx4 bv = *(const floatx4*)(bias + 4 * g);
  floatx4* outv = (floatx4*)out;
#pragma unroll
  for (int nt = 0; nt < 2; ++nt) {
    int s = tile * TILE + n5 + 16 * nt + l15;
    outv[s * 4 + g] = a5[nt] + bv;     // wave's 8 stores cover 1KB contiguous
  }
}

extern "C" void kernel_launch(void* const* d_in, const int* in_sizes, int n_in,
                              void* d_out, int out_size, void* d_ws, size_t ws_size,
                              hipStream_t stream) {
  (void)in_sizes; (void)n_in; (void)out_size; (void)ws_size;
  const float* x    = (const float*)d_in[0];
  const float* W0   = (const float*)d_in[1];
  const float* W1   = (const float*)d_in[2];
  const float* W2   = (const float*)d_in[3];
  const float* W3   = (const float*)d_in[4];
  const float* W4   = (const float*)d_in[5];
  const float* W5   = (const float*)d_in[6];
  const float* bias = (const float*)d_in[7];
  bf16x8* ws = (bf16x8*)d_ws;   // needs 151552 B

  prep_weights<<<(WTOT + 255) / 256, 256, 0, stream>>>(W0, W1, W2, W3, W4, W5, ws);
  mlp_kernel<<<NBLK, 128, 0, stream>>>(x, bias, (const bf16x8*)ws, (float*)d_out);
}